// Round 1
// baseline (145.832 us; speedup 1.0000x reference)
//
#include <hip/hip_runtime.h>

// L0-regularized linear (hard-concrete gate), training path.
// out[b,o] = sum_i x[b,i] * w[o,i] * z[b,o,i] + bias[o]
// z = clip(sigmoid((ln u - ln(1-u) + la)/TEMP) * (ZETA-GAMMA) + GAMMA, 0, 1)
//
// Memory-bound on u (512 MiB read-once). One wave per (b,o) row, float4 loads,
// log2-domain sigmoid (2x v_log, 1x v_exp, 1x v_rcp per element).

#define TEMP_INV   1.5f                   // 1 / (2/3)
#define LOG2E      1.4426950408889634f
#define ZMG        1.2000000476837158f    // ZETA - GAMMA
#define GAM       -0.1f

__global__ __launch_bounds__(256) void l0_gate_linear_kernel(
    const float* __restrict__ x,
    const float* __restrict__ u,
    const float* __restrict__ w,
    const float* __restrict__ la,
    const float* __restrict__ bias,
    float* __restrict__ out,
    int B, int OUT, int IN)
{
    const int wave = (blockIdx.x * blockDim.x + threadIdx.x) >> 6;
    const int lane = threadIdx.x & 63;
    const int total = B * OUT;
    if (wave >= total) return;

    // o-major: 32 consecutive waves share the same o -> w/la rows hit L1/L2.
    const int o = wave >> 5;      // wave / B   (B == 32)
    const int b = wave & 31;      // wave % B

    const float4* __restrict__ u4  = (const float4*)(u  + ((size_t)b * OUT + o) * IN);
    const float4* __restrict__ w4  = (const float4*)(w  + (size_t)o * IN);
    const float4* __restrict__ la4 = (const float4*)(la + (size_t)o * IN);
    const float4* __restrict__ x4  = (const float4*)(x  + (size_t)b * IN);

    const int IN4 = IN >> 2;
    float acc = 0.0f;

    for (int idx = lane; idx < IN4; idx += 64) {
        float4 uu = u4[idx];
        float4 ww = w4[idx];
        float4 ll = la4[idx];
        float4 xx = x4[idx];
        #pragma unroll
        for (int j = 0; j < 4; ++j) {
            float uj = (&uu.x)[j];
            float wj = (&ww.x)[j];
            float lj = (&ll.x)[j];
            float xj = (&xx.x)[j];
            // t * log2(e) = (log2(u) - log2(1-u)) * 1.5 + la * (1.5*log2e)
            float l2 = __builtin_amdgcn_logf(uj) - __builtin_amdgcn_logf(1.0f - uj);
            float t2 = fmaf(l2, TEMP_INV, lj * (TEMP_INV * LOG2E));
            // sigmoid(t) = 1 / (1 + exp2(-t*log2e))
            float e  = __builtin_amdgcn_exp2f(-t2);
            float s  = __builtin_amdgcn_rcpf(1.0f + e);
            float z  = fminf(fmaxf(fmaf(s, ZMG, GAM), 0.0f), 1.0f);
            acc = fmaf(xj * wj, z, acc);
        }
    }

    // wave-64 butterfly reduction
    #pragma unroll
    for (int off = 32; off > 0; off >>= 1)
        acc += __shfl_xor(acc, off, 64);

    if (lane == 0)
        out[(size_t)b * OUT + o] = acc + bias[o];
}

extern "C" void kernel_launch(void* const* d_in, const int* in_sizes, int n_in,
                              void* d_out, int out_size, void* d_ws, size_t ws_size,
                              hipStream_t stream) {
    const float* x    = (const float*)d_in[0];
    const float* u    = (const float*)d_in[1];
    const float* w    = (const float*)d_in[2];
    const float* la   = (const float*)d_in[3];
    const float* bias = (const float*)d_in[4];
    float* out = (float*)d_out;

    const int OUT = in_sizes[4];              // bias
    const int IN  = in_sizes[2] / OUT;        // weight = OUT*IN
    const int B   = in_sizes[0] / IN;         // x = B*IN

    const int total_waves = B * OUT;          // one wave per output element
    const int waves_per_block = 4;            // 256 threads
    const int blocks = (total_waves + waves_per_block - 1) / waves_per_block;

    l0_gate_linear_kernel<<<blocks, 256, 0, stream>>>(x, u, w, la, bias, out,
                                                      B, OUT, IN);
}

// Round 2
// 133.179 us; speedup vs baseline: 1.0950x; 1.0950x over previous
//
#include <hip/hip_runtime.h>

// L0-regularized linear (hard-concrete gate), training path.
// out[b,o] = sum_i x[b,i] * w[o,i] * z[b,o,i] + bias[o]
// z = clip(sigmoid((ln u - ln(1-u) + la)/TEMP) * (ZETA-GAMMA) + GAMMA, 0, 1)
//
// HBM-bound on u (512 MiB, read-once). One wave per (b,o) row.
// R2: XCD-chunked block swizzle (all 8 blocks sharing an `o` land on one XCD
// so w[o]/la[o] are fetched from HBM once, not 8x) + IN=2048 specialization
// (full unroll of the 8-float4 row -> all loads issued up front).
//
// NOTE: __builtin_amdgcn_logf/expf are v_log_f32/v_exp_f32 = base-2 ops.
// Math below is in log2 domain: t2 = log2(u/(1-u))*1.5 + la*(1.5*log2e),
// sigmoid = rcp(1 + exp2(-t2)).  Verified: absmax 0.25 vs threshold 2.49.

#define TEMP_INV   1.5f                   // 1 / (2/3)
#define LOG2E      1.4426950408889634f
#define ZMG        1.2000000476837158f    // ZETA - GAMMA
#define GAM       -0.1f

__device__ __forceinline__ float gate_term(float uj, float wj, float lj, float xj) {
    float l2 = __builtin_amdgcn_logf(uj) - __builtin_amdgcn_logf(1.0f - uj); // log2 ratio
    float t2 = fmaf(l2, TEMP_INV, lj * (TEMP_INV * LOG2E));
    float e  = __builtin_amdgcn_exp2f(-t2);
    float s  = __builtin_amdgcn_rcpf(1.0f + e);
    float z  = fminf(fmaxf(fmaf(s, ZMG, GAM), 0.0f), 1.0f);
    return xj * wj * z;
}

// Specialized: B==32, IN==2048, grid = B*OUT/4 blocks, multiple of 8.
template <int IN>
__global__ __launch_bounds__(256) void l0_gate_linear_swz(
    const float* __restrict__ x,
    const float* __restrict__ u,
    const float* __restrict__ w,
    const float* __restrict__ la,
    const float* __restrict__ bias,
    float* __restrict__ out,
    int OUT, int chunks_per_xcd)
{
    // XCD-chunked bijective swizzle: XCD (i&7) gets a contiguous block range.
    const int i   = blockIdx.x;
    const int swz = (i & 7) * chunks_per_xcd + (i >> 3);

    const int widx = threadIdx.x >> 6;
    const int lane = threadIdx.x & 63;
    const int wave = swz * 4 + widx;

    const int o = wave >> 5;      // wave / B, B == 32
    const int b = wave & 31;

    const float4* __restrict__ u4  = (const float4*)(u  + ((size_t)b * OUT + o) * IN) + lane;
    const float4* __restrict__ w4  = (const float4*)(w  + (size_t)o * IN) + lane;
    const float4* __restrict__ la4 = (const float4*)(la + (size_t)o * IN) + lane;
    const float4* __restrict__ x4  = (const float4*)(x  + (size_t)b * IN) + lane;

    constexpr int ITERS = IN / 4 / 64;    // 8 for IN=2048

    float4 uu[ITERS], ww[ITERS], ll[ITERS], xx[ITERS];
    #pragma unroll
    for (int k = 0; k < ITERS; ++k) uu[k] = u4[64 * k];    // HBM-miss stream first
    #pragma unroll
    for (int k = 0; k < ITERS; ++k) ww[k] = w4[64 * k];
    #pragma unroll
    for (int k = 0; k < ITERS; ++k) ll[k] = la4[64 * k];
    #pragma unroll
    for (int k = 0; k < ITERS; ++k) xx[k] = x4[64 * k];

    float acc = 0.0f;
    #pragma unroll
    for (int k = 0; k < ITERS; ++k) {
        #pragma unroll
        for (int j = 0; j < 4; ++j)
            acc += gate_term((&uu[k].x)[j], (&ww[k].x)[j], (&ll[k].x)[j], (&xx[k].x)[j]);
    }

    #pragma unroll
    for (int off = 32; off > 0; off >>= 1)
        acc += __shfl_xor(acc, off, 64);

    if (lane == 0)
        out[(size_t)b * OUT + o] = acc + bias[o];
}

// Generic fallback (any shapes), no swizzle.
__global__ __launch_bounds__(256) void l0_gate_linear_gen(
    const float* __restrict__ x,
    const float* __restrict__ u,
    const float* __restrict__ w,
    const float* __restrict__ la,
    const float* __restrict__ bias,
    float* __restrict__ out,
    int B, int OUT, int IN)
{
    const int wave = (blockIdx.x * blockDim.x + threadIdx.x) >> 6;
    const int lane = threadIdx.x & 63;
    if (wave >= B * OUT) return;
    const int o = wave / B;
    const int b = wave % B;

    const float* ur = u  + ((size_t)b * OUT + o) * IN;
    const float* wr = w  + (size_t)o * IN;
    const float* lr = la + (size_t)o * IN;
    const float* xr = x  + (size_t)b * IN;

    float acc = 0.0f;
    for (int idx = lane; idx < IN; idx += 64)
        acc += gate_term(ur[idx], wr[idx], lr[idx], xr[idx]);

    #pragma unroll
    for (int off = 32; off > 0; off >>= 1)
        acc += __shfl_xor(acc, off, 64);

    if (lane == 0)
        out[(size_t)b * OUT + o] = acc + bias[o];
}

extern "C" void kernel_launch(void* const* d_in, const int* in_sizes, int n_in,
                              void* d_out, int out_size, void* d_ws, size_t ws_size,
                              hipStream_t stream) {
    const float* x    = (const float*)d_in[0];
    const float* u    = (const float*)d_in[1];
    const float* w    = (const float*)d_in[2];
    const float* la   = (const float*)d_in[3];
    const float* bias = (const float*)d_in[4];
    float* out = (float*)d_out;

    const int OUT = in_sizes[4];              // bias
    const int IN  = in_sizes[2] / OUT;        // weight = OUT*IN
    const int B   = in_sizes[0] / IN;         // x = B*IN

    const int total_waves = B * OUT;
    const int blocks = (total_waves + 3) / 4; // 4 waves (256 threads) per block

    if (B == 32 && IN == 2048 && (blocks & 7) == 0) {
        l0_gate_linear_swz<2048><<<blocks, 256, 0, stream>>>(
            x, u, w, la, bias, out, OUT, blocks / 8);
    } else {
        l0_gate_linear_gen<<<blocks, 256, 0, stream>>>(
            x, u, w, la, bias, out, B, OUT, IN);
    }
}

// Round 3
// 131.274 us; speedup vs baseline: 1.1109x; 1.0145x over previous
//
#include <hip/hip_runtime.h>

// L0-regularized linear (hard-concrete gate), training path.
// out[b,o] = sum_i x[b,i] * w[o,i] * z[b,o,i] + bias[o]
// z = clip(sigmoid((ln u - ln(1-u) + la)/TEMP) * (ZETA-GAMMA) + GAMMA, 0, 1)
//
// R3: persistent waves. One wave per (o, 16-row b-slice): w[o]/la[o] held in
// registers across all 16 rows (la pre-scaled by 1.5*log2e), u streamed with a
// 2-deep register double-buffer (prefetch row r+1 while computing row r; full
// unroll keeps all buffer indices compile-time -> no scratch). 64-thread
// blocks, __launch_bounds__(64,3) caps VGPRs ~170 -> ~12 waves/CU, each with
// 8 KiB of u in flight. XCD-chunked swizzle keeps o-sharing waves on one XCD.
//
// log2-domain math: v_log/v_exp are base-2. t2 = log2(u/(1-u))*1.5 + la',
// la' = la*1.5*log2e; sigmoid = rcp(1+exp2(-t2)). Verified absmax 0.25.

#define TEMP_INV   1.5f
#define LOG2E      1.4426950408889634f
#define LA_SCALE   (TEMP_INV * LOG2E)
#define ZMG        1.2000000476837158f    // ZETA - GAMMA
#define GAM       -0.1f

__device__ __forceinline__ float gate_term(float uj, float wj, float lj, float xj) {
    float l2 = __builtin_amdgcn_logf(uj) - __builtin_amdgcn_logf(1.0f - uj);
    float t2 = fmaf(l2, TEMP_INV, lj);                 // lj pre-scaled
    float e  = __builtin_amdgcn_exp2f(-t2);
    float s  = __builtin_amdgcn_rcpf(1.0f + e);
    float z  = fminf(fmaxf(fmaf(s, ZMG, GAM), 0.0f), 1.0f);
    return xj * wj * z;
}

// One wave (64-thread block) per (o, BPW-row b-slice). B == nslice*BPW == 32.
template <int IN, int BPW>
__global__ __launch_bounds__(64, 3) void l0_owave(
    const float* __restrict__ x,
    const float* __restrict__ u,
    const float* __restrict__ w,
    const float* __restrict__ la,
    const float* __restrict__ bias,
    float* __restrict__ out,
    int OUT, int chunks_per_xcd)
{
    constexpr int K = IN / 256;            // float4s per lane per row (8)
    constexpr int NSLICE = 32 / BPW;       // waves per o (2)

    const int i    = blockIdx.x;
    const int wid  = (i & 7) * chunks_per_xcd + (i >> 3);   // bijective swizzle
    const int lane = threadIdx.x;                            // 0..63

    const int o  = wid / NSLICE;
    const int b0 = (wid % NSLICE) * BPW;

    const float bo = bias[o];

    // w[o], la[o] -> registers, la pre-scaled.
    const float4* w4  = (const float4*)(w  + (size_t)o * IN) + lane;
    const float4* la4 = (const float4*)(la + (size_t)o * IN) + lane;
    float4 wf[K], lf[K];
    #pragma unroll
    for (int k = 0; k < K; ++k) wf[k] = w4[64 * k];
    #pragma unroll
    for (int k = 0; k < K; ++k) lf[k] = la4[64 * k];
    #pragma unroll
    for (int k = 0; k < K; ++k) {
        lf[k].x *= LA_SCALE; lf[k].y *= LA_SCALE;
        lf[k].z *= LA_SCALE; lf[k].w *= LA_SCALE;
    }

    const size_t urow = (size_t)OUT * (IN / 4);     // float4 stride between b rows
    const float4* ub0 = (const float4*)u + ((size_t)b0 * OUT + o) * (IN / 4) + lane;
    const float4* xb0 = (const float4*)x + (size_t)b0 * (IN / 4) + lane;

    // 2-deep double buffer; full unroll => all indices compile-time constant.
    float4 ubuf[2][K];
    #pragma unroll
    for (int k = 0; k < K; ++k) ubuf[0][k] = ub0[64 * k];

    #pragma unroll
    for (int r = 0; r < BPW; ++r) {
        if (r + 1 < BPW) {                          // prefetch next u row
            const float4* un = ub0 + (size_t)(r + 1) * urow;
            #pragma unroll
            for (int k = 0; k < K; ++k) ubuf[(r + 1) & 1][k] = un[64 * k];
        }
        const float4* xr = xb0 + (size_t)r * (IN / 4);
        float acc = 0.0f;
        #pragma unroll
        for (int k = 0; k < K; ++k) {
            float4 xx = xr[64 * k];
            float4 uu = ubuf[r & 1][k];
            #pragma unroll
            for (int j = 0; j < 4; ++j)
                acc += gate_term((&uu.x)[j], (&wf[k].x)[j], (&lf[k].x)[j], (&xx.x)[j]);
        }
        #pragma unroll
        for (int off = 32; off > 0; off >>= 1)
            acc += __shfl_xor(acc, off, 64);
        if (lane == 0)
            out[(size_t)(b0 + r) * OUT + o] = acc + bo;
    }
}

// Generic fallback (any shapes).
__global__ __launch_bounds__(256) void l0_gate_linear_gen(
    const float* __restrict__ x,
    const float* __restrict__ u,
    const float* __restrict__ w,
    const float* __restrict__ la,
    const float* __restrict__ bias,
    float* __restrict__ out,
    int B, int OUT, int IN)
{
    const int wave = (blockIdx.x * blockDim.x + threadIdx.x) >> 6;
    const int lane = threadIdx.x & 63;
    if (wave >= B * OUT) return;
    const int o = wave / B;
    const int b = wave % B;

    const float* ur = u  + ((size_t)b * OUT + o) * IN;
    const float* wr = w  + (size_t)o * IN;
    const float* lr = la + (size_t)o * IN;
    const float* xr = x  + (size_t)b * IN;

    float acc = 0.0f;
    for (int idx = lane; idx < IN; idx += 64)
        acc += gate_term(ur[idx], wr[idx] , lr[idx] * LA_SCALE, xr[idx]);

    #pragma unroll
    for (int off = 32; off > 0; off >>= 1)
        acc += __shfl_xor(acc, off, 64);

    if (lane == 0)
        out[(size_t)b * OUT + o] = acc + bias[o];
}

extern "C" void kernel_launch(void* const* d_in, const int* in_sizes, int n_in,
                              void* d_out, int out_size, void* d_ws, size_t ws_size,
                              hipStream_t stream) {
    const float* x    = (const float*)d_in[0];
    const float* u    = (const float*)d_in[1];
    const float* w    = (const float*)d_in[2];
    const float* la   = (const float*)d_in[3];
    const float* bias = (const float*)d_in[4];
    float* out = (float*)d_out;

    const int OUT = in_sizes[4];              // bias
    const int IN  = in_sizes[2] / OUT;        // weight = OUT*IN
    const int B   = in_sizes[0] / IN;         // x = B*IN

    constexpr int BPW = 16;                   // b-rows per wave
    const int blocks = OUT * (32 / BPW);      // one 64-thread wave per block

    if (B == 32 && IN == 2048 && (blocks & 7) == 0) {
        l0_owave<2048, BPW><<<blocks, 64, 0, stream>>>(
            x, u, w, la, bias, out, OUT, blocks / 8);
    } else {
        const int total_waves = B * OUT;
        const int gblocks = (total_waves + 3) / 4;
        l0_gate_linear_gen<<<gblocks, 256, 0, stream>>>(
            x, u, w, la, bias, out, B, OUT, IN);
    }
}